// Round 7
// baseline (266.465 us; speedup 1.0000x reference)
//
#include <hip/hip_runtime.h>

constexpr int NQ = 512;
constexpr int NKV = 512;
constexpr int Hh = 16;
constexpr int Dd = 256;

// C = A @ W^T + bias. M=4096, N=256, K=256. BM=BN=64, BK=64.
__global__ __launch_bounds__(256) void gemm_bias(
    const float* __restrict__ A, const float* __restrict__ W,
    const float* __restrict__ bias, float* __restrict__ C) {
  __shared__ float As[64][68];
  __shared__ float Ws[64][68];
  const int t = threadIdx.x;
  const int tx = t & 15, ty = t >> 4;
  const int m0 = blockIdx.x * 64, n0 = blockIdx.y * 64;

  float acc[4][4] = {};
  float4 av[4], wv[4];

#pragma unroll
  for (int i = 0; i < 4; ++i) {
    const int flat = i * 256 + t;
    const int r = flat >> 4, c4 = (flat & 15) << 2;
    av[i] = *(const float4*)(A + (size_t)(m0 + r) * 256 + c4);
    wv[i] = *(const float4*)(W + (size_t)(n0 + r) * 256 + c4);
  }

  for (int kb = 0; kb < 4; ++kb) {
#pragma unroll
    for (int i = 0; i < 4; ++i) {
      const int flat = i * 256 + t;
      const int r = flat >> 4, c4 = (flat & 15) << 2;
      As[c4 + 0][r] = av[i].x; As[c4 + 1][r] = av[i].y;
      As[c4 + 2][r] = av[i].z; As[c4 + 3][r] = av[i].w;
      Ws[c4 + 0][r] = wv[i].x; Ws[c4 + 1][r] = wv[i].y;
      Ws[c4 + 2][r] = wv[i].z; Ws[c4 + 3][r] = wv[i].w;
    }
    __syncthreads();
    if (kb < 3) {
#pragma unroll
      for (int i = 0; i < 4; ++i) {
        const int flat = i * 256 + t;
        const int r = flat >> 4, c4 = (flat & 15) << 2;
        av[i] = *(const float4*)(A + (size_t)(m0 + r) * 256 + (kb + 1) * 64 + c4);
        wv[i] = *(const float4*)(W + (size_t)(n0 + r) * 256 + (kb + 1) * 64 + c4);
      }
    }
#pragma unroll 16
    for (int k = 0; k < 64; ++k) {
      float a_[4], w_[4];
      *(float4*)a_ = *(const float4*)&As[k][ty << 2];
      *(float4*)w_ = *(const float4*)&Ws[k][tx << 2];
#pragma unroll
      for (int i = 0; i < 4; ++i)
#pragma unroll
        for (int j = 0; j < 4; ++j)
          acc[i][j] = fmaf(a_[i], w_[j], acc[i][j]);
    }
    if (kb < 3) __syncthreads();
  }

  const float4 bv = *(const float4*)(bias + n0 + (tx << 2));
  const float bb[4] = {bv.x, bv.y, bv.z, bv.w};
#pragma unroll
  for (int i = 0; i < 4; ++i) {
    float4 cv;
    cv.x = acc[i][0] + bb[0]; cv.y = acc[i][1] + bb[1];
    cv.z = acc[i][2] + bb[2]; cv.w = acc[i][3] + bb[3];
    *(float4*)(C + (size_t)(m0 + (ty << 2) + i) * 256 + n0 + (tx << 2)) = cv;
  }
}

// Fused masked softmax + per-head aggregation + L2 rescale. v8:
// - NO P staging at all: each wave's P slice is a coalesced global b128
//   from L2-resident proj (cuts the LDS pipe from ~20 inst/wave-round to
//   ~12 and removes the DMA drain coupling entirely).
// - Block = 4 q-rows (grid 128x8 = 1024 blocks = 4 independent blocks/CU
//   at 40 KB LDS, 32 waves/CU): barrier stalls covered by 3 other blocks.
// - 8 coarse rounds (16 k/oct), E double-buffered, ONE __syncthreads per
//   round; its vmcnt drain covers only the msg prefetch issued a full
//   round earlier.
// - Registers: o/s/r named scalars + pairwise P (16 live max) ~ 58 VGPR;
//   #pragma unroll 1 on rd/kq loops prevents hoist-spill. Spill canary:
//   WRITE_SIZE must be ~4 MB.
__global__ __launch_bounds__(512) void attn_fused(
    const float* __restrict__ msg, const int* __restrict__ adj,
    const float* __restrict__ proj, float* __restrict__ attn_out) {
  __shared__ float Esh[2][4][4][16][20];  // 40 KB: [buf][oct][q][h^q][k(16)+pad]

  const int t    = threadIdx.x;
  const int lane = t & 63;
  const int w    = t >> 6;      // wave 0..7
  const int oct  = w >> 1;      // k-quarter for FMA
  const int qh   = w & 1;       // q-half (2 rows) for FMA
  const int h    = lane >> 2;
  const int d4   = lane & 3;
  const int col  = lane << 2;   // = h*16 + d4*4
  const int q0   = blockIdx.x * 4;
  const int b    = blockIdx.y;

  // E-production decomposition: thread -> (h4, q, oct, k-pair)
  const int p_h4  = t & 3;
  const int p_q   = (t >> 2) & 3;
  const int p_oct = (t >> 4) & 3;
  const int p_kp  = t >> 6;     // 0..7 (k-pair within oct's 16 rows)

  const float* mrow  = msg + ((size_t)(b * NQ + q0 + p_q) * NKV) * Hh + p_h4 * 4;
  const int*   arow  = adj + (size_t)(b * NQ + q0 + p_q) * NKV;
  const float* pbase = proj + (size_t)b * NKV * Dd;

  float4 o0 = {}, o1 = {};
  float s0 = 0.f, s1 = 0.f, r0 = 0.f, r1 = 0.f;

  float4 mv0, mv1;
  int2 aa;

  const int ql0 = qh * 2, ql1 = qh * 2 + 1;
  const int eh0 = h ^ ql0, eh1 = h ^ ql1;

  // ---- prologue: msg(0) -> E(0) -> Esh[0]; sync ----
  {
    const int kg = p_oct * 128 + p_kp * 2;
    mv0 = *(const float4*)(mrow + (size_t)kg * Hh);
    mv1 = *(const float4*)(mrow + (size_t)(kg + 1) * Hh);
    aa = *(const int2*)(arow + kg);
    float e0[4], e1[4];
    e0[0] = aa.x > 0 ? __expf(mv0.x) : 0.f; e0[1] = aa.x > 0 ? __expf(mv0.y) : 0.f;
    e0[2] = aa.x > 0 ? __expf(mv0.z) : 0.f; e0[3] = aa.x > 0 ? __expf(mv0.w) : 0.f;
    e1[0] = aa.y > 0 ? __expf(mv1.x) : 0.f; e1[1] = aa.y > 0 ? __expf(mv1.y) : 0.f;
    e1[2] = aa.y > 0 ? __expf(mv1.z) : 0.f; e1[3] = aa.y > 0 ? __expf(mv1.w) : 0.f;
#pragma unroll
    for (int i = 0; i < 4; ++i) {
      const int h2 = (p_h4 * 4 + i) ^ p_q;
      *(float2*)&Esh[0][p_oct][p_q][h2][p_kp * 2] = make_float2(e0[i], e1[i]);
    }
  }
  __syncthreads();

#pragma unroll 1
  for (int rd = 0; rd < 8; ++rd) {
    const int cur = rd & 1, nxt = cur ^ 1;
    // msg(rd+1) prefetch: full round of latency cover before use.
    if (rd < 7) {
      const int kg = p_oct * 128 + (rd + 1) * 16 + p_kp * 2;
      mv0 = *(const float4*)(mrow + (size_t)kg * Hh);
      mv1 = *(const float4*)(mrow + (size_t)(kg + 1) * Hh);
      aa = *(const int2*)(arow + kg);
    }

    // ---- FMA(rd): 16 k-rows of this oct; P from global (L2), pairwise ----
    __builtin_amdgcn_s_setprio(1);
#pragma unroll 1
    for (int kq = 0; kq < 4; ++kq) {
      const float* prow =
          pbase + (size_t)(oct * 128 + rd * 16 + kq * 4) * Dd + col;
      const float4 p0 = *(const float4*)(prow);
      const float4 p1 = *(const float4*)(prow + Dd);
      const float4 p2 = *(const float4*)(prow + 2 * Dd);
      const float4 p3 = *(const float4*)(prow + 3 * Dd);
      const float4 ea = *(const float4*)&Esh[cur][oct][ql0][eh0][kq * 4];
      const float4 eb = *(const float4*)&Esh[cur][oct][ql1][eh1][kq * 4];
      s0 += ea.x + ea.y + ea.z + ea.w;
      r0 = fmaf(ea.x, ea.x, fmaf(ea.y, ea.y,
           fmaf(ea.z, ea.z, fmaf(ea.w, ea.w, r0))));
      o0.x = fmaf(ea.x, p0.x, o0.x); o0.y = fmaf(ea.x, p0.y, o0.y);
      o0.z = fmaf(ea.x, p0.z, o0.z); o0.w = fmaf(ea.x, p0.w, o0.w);
      o0.x = fmaf(ea.y, p1.x, o0.x); o0.y = fmaf(ea.y, p1.y, o0.y);
      o0.z = fmaf(ea.y, p1.z, o0.z); o0.w = fmaf(ea.y, p1.w, o0.w);
      o0.x = fmaf(ea.z, p2.x, o0.x); o0.y = fmaf(ea.z, p2.y, o0.y);
      o0.z = fmaf(ea.z, p2.z, o0.z); o0.w = fmaf(ea.z, p2.w, o0.w);
      o0.x = fmaf(ea.w, p3.x, o0.x); o0.y = fmaf(ea.w, p3.y, o0.y);
      o0.z = fmaf(ea.w, p3.z, o0.z); o0.w = fmaf(ea.w, p3.w, o0.w);
      s1 += eb.x + eb.y + eb.z + eb.w;
      r1 = fmaf(eb.x, eb.x, fmaf(eb.y, eb.y,
           fmaf(eb.z, eb.z, fmaf(eb.w, eb.w, r1))));
      o1.x = fmaf(eb.x, p0.x, o1.x); o1.y = fmaf(eb.x, p0.y, o1.y);
      o1.z = fmaf(eb.x, p0.z, o1.z); o1.w = fmaf(eb.x, p0.w, o1.w);
      o1.x = fmaf(eb.y, p1.x, o1.x); o1.y = fmaf(eb.y, p1.y, o1.y);
      o1.z = fmaf(eb.y, p1.z, o1.z); o1.w = fmaf(eb.y, p1.w, o1.w);
      o1.x = fmaf(eb.z, p2.x, o1.x); o1.y = fmaf(eb.z, p2.y, o1.y);
      o1.z = fmaf(eb.z, p2.z, o1.z); o1.w = fmaf(eb.z, p2.w, o1.w);
      o1.x = fmaf(eb.w, p3.x, o1.x); o1.y = fmaf(eb.w, p3.y, o1.y);
      o1.z = fmaf(eb.w, p3.z, o1.z); o1.w = fmaf(eb.w, p3.w, o1.w);
    }
    __builtin_amdgcn_s_setprio(0);

    // ---- E(rd+1) -> Esh[nxt] (WAR: its readers finished before sync(rd-1)) ----
    if (rd < 7) {
      float e0[4], e1[4];
      e0[0] = aa.x > 0 ? __expf(mv0.x) : 0.f; e0[1] = aa.x > 0 ? __expf(mv0.y) : 0.f;
      e0[2] = aa.x > 0 ? __expf(mv0.z) : 0.f; e0[3] = aa.x > 0 ? __expf(mv0.w) : 0.f;
      e1[0] = aa.y > 0 ? __expf(mv1.x) : 0.f; e1[1] = aa.y > 0 ? __expf(mv1.y) : 0.f;
      e1[2] = aa.y > 0 ? __expf(mv1.z) : 0.f; e1[3] = aa.y > 0 ? __expf(mv1.w) : 0.f;
#pragma unroll
      for (int i = 0; i < 4; ++i) {
        const int h2 = (p_h4 * 4 + i) ^ p_q;
        *(float2*)&Esh[nxt][p_oct][p_q][h2][p_kp * 2] = make_float2(e0[i], e1[i]);
      }
    }
    __syncthreads();  // publish Esh[nxt]; drains only the msg prefetch
  }

  // ---- epilogue: tree-reduce (o,s,r) over the 4 k-quarters ----
  float* base = &Esh[0][0][0][0][0];
  float4* Ro = (float4*)base;      // 8 KB (512 float4)
  float*  Rs = base + 2048;        // 128 floats
  float*  Rr = base + 2176;        // 128 floats

  __syncthreads();
  if (w >= 4) {  // oct 2,3 -> regions 0..3 (w-4), 2 qi each
    const int reg = w - 4;
    Ro[(reg * 2 + 0) * 64 + lane] = o0;
    Ro[(reg * 2 + 1) * 64 + lane] = o1;
    if (d4 == 0) {
      Rs[(reg * 2 + 0) * 16 + h] = s0; Rs[(reg * 2 + 1) * 16 + h] = s1;
      Rr[(reg * 2 + 0) * 16 + h] = r0; Rr[(reg * 2 + 1) * 16 + h] = r1;
    }
  }
  __syncthreads();
  if (w < 4) {
    const float4 v0 = Ro[(w * 2 + 0) * 64 + lane];
    const float4 v1 = Ro[(w * 2 + 1) * 64 + lane];
    o0.x += v0.x; o0.y += v0.y; o0.z += v0.z; o0.w += v0.w;
    o1.x += v1.x; o1.y += v1.y; o1.z += v1.z; o1.w += v1.w;
    s0 += Rs[(w * 2 + 0) * 16 + h]; s1 += Rs[(w * 2 + 1) * 16 + h];
    r0 += Rr[(w * 2 + 0) * 16 + h]; r1 += Rr[(w * 2 + 1) * 16 + h];
  }
  __syncthreads();
  if (w == 2 || w == 3) {  // oct 1 -> regions 0,1
    const int reg = w - 2;
    Ro[(reg * 2 + 0) * 64 + lane] = o0;
    Ro[(reg * 2 + 1) * 64 + lane] = o1;
    if (d4 == 0) {
      Rs[(reg * 2 + 0) * 16 + h] = s0; Rs[(reg * 2 + 1) * 16 + h] = s1;
      Rr[(reg * 2 + 0) * 16 + h] = r0; Rr[(reg * 2 + 1) * 16 + h] = r1;
    }
  }
  __syncthreads();
  if (w < 2) {
    const float4 v0 = Ro[(w * 2 + 0) * 64 + lane];
    const float4 v1 = Ro[(w * 2 + 1) * 64 + lane];
    o0.x += v0.x; o0.y += v0.y; o0.z += v0.z; o0.w += v0.w;
    o1.x += v1.x; o1.y += v1.y; o1.z += v1.z; o1.w += v1.w;
    const float st0 = s0 + Rs[(w * 2 + 0) * 16 + h];
    const float st1 = s1 + Rs[(w * 2 + 1) * 16 + h];
    const float rt0 = r0 + Rr[(w * 2 + 0) * 16 + h];
    const float rt1 = r1 + Rr[(w * 2 + 1) * 16 + h];
    const float wg0 = sqrtf(rt0) / (st0 * st0);
    const float wg1 = sqrtf(rt1) / (st1 * st1);
    float4 u0, u1;
    u0.x = o0.x * wg0; u0.y = o0.y * wg0; u0.z = o0.z * wg0; u0.w = o0.w * wg0;
    u1.x = o1.x * wg1; u1.y = o1.y * wg1; u1.z = o1.z * wg1; u1.w = o1.w * wg1;
    *(float4*)(attn_out + (size_t)(b * NQ + q0 + w * 2 + 0) * Dd + col) = u0;
    *(float4*)(attn_out + (size_t)(b * NQ + q0 + w * 2 + 1) * Dd + col) = u1;
  }
}

extern "C" void kernel_launch(void* const* d_in, const int* in_sizes, int n_in,
                              void* d_out, int out_size, void* d_ws, size_t ws_size,
                              hipStream_t stream) {
  const float* v_inv    = (const float*)d_in[0];
  const float* messages = (const float*)d_in[1];
  const int*   adj      = (const int*)d_in[2];
  const float* W_in     = (const float*)d_in[3];
  const float* b_in     = (const float*)d_in[4];
  const float* W_out    = (const float*)d_in[5];
  const float* b_out    = (const float*)d_in[6];
  float* out = (float*)d_out;

  float* proj = (float*)d_ws;                      // 4 MB [B,NKV,D]
  float* attn = proj + (size_t)8 * NKV * Dd;       // 4 MB [B,NQ,D]

  dim3 gg(64, 4);
  gemm_bias<<<gg, 256, 0, stream>>>(v_inv, W_in, b_in, proj);
  attn_fused<<<dim3(128, 8), 512, 0, stream>>>(messages, adj, proj, attn);
  gemm_bias<<<gg, 256, 0, stream>>>(attn, W_out, b_out, out);
}